// Round 9
// baseline (642.799 us; speedup 1.0000x reference)
//
#include <hip/hip_runtime.h>
#include <hip/hip_bf16.h>

#define BB 4
#define SS 4096
#define EE 64
#define DD 512
#define KVBLK 32
#define NQT 32  // KV tiles per quarter

typedef __attribute__((ext_vector_type(4))) float f32x4;
typedef __attribute__((ext_vector_type(8))) _Float16 f16x8;
typedef unsigned short u16;
typedef unsigned int u32;

__device__ __forceinline__ u16 f2h(float f) {
  _Float16 h = (_Float16)f;
  return __builtin_bit_cast(u16, h);
}
__device__ __forceinline__ float h2f(u16 b) {
  return (float)__builtin_bit_cast(_Float16, b);
}

__device__ __forceinline__ void async16(const void* g, void* l) {
  __builtin_amdgcn_global_load_lds(
      (const __attribute__((address_space(1))) void*)g,
      (__attribute__((address_space(3))) void*)l, 16, 0, 0);
}

// ---------------- K1: q,k projection (fp32 VALU), emit fp16 ----------------
__global__ __launch_bounds__(256) void qk_proj(
    const float* __restrict__ x,
    const float* __restrict__ Wq, const float* __restrict__ bq,
    const float* __restrict__ Wk, const float* __restrict__ bk,
    u16* __restrict__ qb, u16* __restrict__ kb) {
  __shared__ float xs[32][EE];
  const int tid = threadIdx.x;
  const int row0 = blockIdx.x * 32;
  const float* W = blockIdx.y ? Wk : Wq;
  const float* bias = blockIdx.y ? bk : bq;
  u16* dst = blockIdx.y ? kb : qb;

  #pragma unroll
  for (int i = 0; i < 2; ++i) {
    int idx = tid + 256 * i;
    int r = idx >> 4, c = (idx & 15) * 4;
    *(float4*)&xs[r][c] = *(const float4*)&x[(size_t)(row0 + r) * EE + c];
  }
  __syncthreads();

  const int col = (tid & 127) * 4;
  const int rg = (tid >> 7) * 16;
  float acc[16][4];
  #pragma unroll
  for (int r = 0; r < 16; ++r)
    #pragma unroll
    for (int j = 0; j < 4; ++j) acc[r][j] = 0.f;

  for (int k = 0; k < EE; k += 4) {
    float4 wr[4];
    #pragma unroll
    for (int j = 0; j < 4; ++j) wr[j] = *(const float4*)&W[(size_t)(k + j) * DD + col];
    #pragma unroll
    for (int r = 0; r < 16; ++r) {
      float4 xv = *(const float4*)&xs[rg + r][k];
      acc[r][0] += xv.x * wr[0].x + xv.y * wr[1].x + xv.z * wr[2].x + xv.w * wr[3].x;
      acc[r][1] += xv.x * wr[0].y + xv.y * wr[1].y + xv.z * wr[2].y + xv.w * wr[3].y;
      acc[r][2] += xv.x * wr[0].z + xv.y * wr[1].z + xv.z * wr[2].z + xv.w * wr[3].z;
      acc[r][3] += xv.x * wr[0].w + xv.y * wr[1].w + xv.z * wr[2].w + xv.w * wr[3].w;
    }
  }

  const float4 b4 = *(const float4*)&bias[col];
  #pragma unroll
  for (int r = 0; r < 16; ++r) {
    ushort4 o;
    o.x = f2h(acc[r][0] + b4.x);
    o.y = f2h(acc[r][1] + b4.y);
    o.z = f2h(acc[r][2] + b4.z);
    o.w = f2h(acc[r][3] + b4.w);
    *(ushort4*)&dst[(size_t)(row0 + rg + r) * DD + col] = o;
  }
}

// ---------------- K1b: Wf = Wv @ Wo  (64x64), bf = bv @ Wo ----------------
__global__ __launch_bounds__(256) void wfuse(
    const float* __restrict__ Wv, const float* __restrict__ bv,
    const float* __restrict__ Wo, float* __restrict__ Wf, float* __restrict__ bf) {
  const int tid = threadIdx.x;
  const int e = tid & 63, dg = tid >> 6;  // 4 d-groups x 16
  #pragma unroll 1
  for (int dd = 0; dd < 16; ++dd) {
    int d = dg * 16 + dd;
    float a = 0.f;
    for (int k = 0; k < DD; ++k) a += Wv[(size_t)e * DD + k] * Wo[(size_t)k * EE + d];
    Wf[e * EE + d] = a;
  }
  if (tid < EE) {
    float a = 0.f;
    for (int k = 0; k < DD; ++k) a += bv[k] * Wo[(size_t)k * EE + tid];
    bf[tid] = a;
  }
}

// ---------------- K1c: VWt[b][d][s] = (x @ Wf + bf)^T, fp16 ----------------
__global__ __launch_bounds__(256) void vw_proj(
    const float* __restrict__ x, const float* __restrict__ Wf,
    const float* __restrict__ bf, u16* __restrict__ vwt) {
  __shared__ float xs[64][EE];
  __shared__ float wfs[EE][64];
  __shared__ float bfs[64];
  const int tid = threadIdx.x;
  const int b = blockIdx.x & 3;
  const int s0 = (blockIdx.x >> 2) * 64;

  #pragma unroll
  for (int i = 0; i < 4; ++i) {
    int idx = tid + 256 * i;
    int r = idx >> 4, c = (idx & 15) * 4;
    *(float4*)&xs[r][c] = *(const float4*)&x[((size_t)b * SS + s0 + r) * EE + c];
    *(float4*)&wfs[r][c] = *(const float4*)&Wf[(size_t)r * 64 + c];
  }
  if (tid < 64) bfs[tid] = bf[tid];
  __syncthreads();

  const int d = tid & 63, sg = tid >> 6;
  float acc[16];
  #pragma unroll
  for (int i = 0; i < 16; ++i) acc[i] = bfs[d];
  for (int e = 0; e < EE; ++e) {
    float wv = wfs[e][d];
    #pragma unroll
    for (int i = 0; i < 16; ++i) acc[i] += xs[sg * 16 + i][e] * wv;
  }
  u16* dst = vwt + ((size_t)b * 64 + d) * SS + s0 + sg * 16;
  union { uint4 u[2]; u16 hh[16]; } o;
  #pragma unroll
  for (int i = 0; i < 16; ++i) o.hh[i] = f2h(acc[i]);
  *(uint4*)dst = o.u[0];
  *(uint4*)(dst + 8) = o.u[1];
}

// ---------------- K2: flash attention v7 (fused VW, d=64, 4 blocks/CU) ----------------
// 1024 blocks x 256 thr (4 warps x 16q = 64 q-rows). bid&15 = (batch, kv-quarter).
// Q in regs; swapped QK^T; warp-private softmax; PV vs VW (d=64) from L2;
// K single-buffered async16, staged right after QK-reads barrier.
__global__ __launch_bounds__(256, 4) void attn_fwd(
    const u16* __restrict__ qbuf, const u16* __restrict__ kbuf,
    const u16* __restrict__ vwt, const float* __restrict__ mask,
    float* __restrict__ opart, float* __restrict__ stats) {
  __shared__ u16 KsS[32 * 512];       // 32768 B
  __shared__ u16 PsS[4 * 16 * 36];    // 4608 B

  const int tid = threadIdx.x;
  const int lane = tid & 63;
  const int w = tid >> 6;  // 0..3
  const int lrow = lane & 15, lhi = lane >> 4;

  const int bid = blockIdx.x;
  const int grp = bid & 15;
  const int b = grp >> 2, qt = grp & 3;
  const int q0 = (bid >> 4) * 64;
  const int tbase = qt * (SS / 4);

  const int qrow = q0 + w * 16 + lrow;

  // ---- Q -> registers (B-operand frags) ----
  f16x8 qreg[16];
  {
    const u16* qg = qbuf + ((size_t)b * SS + qrow) * DD + lhi * 8;
    #pragma unroll
    for (int kk = 0; kk < 16; ++kk) qreg[kk] = *(const f16x8*)(qg + kk * 32);
  }

  auto stage_k = [&](int t0n) {
    const char* kg = (const char*)(kbuf + ((size_t)b * SS + t0n) * DD);
    #pragma unroll
    for (int rr = 0; rr < 8; ++rr) {
      int row = w * 8 + rr;
      async16(kg + (size_t)row * 1024 + ((lane * 16) ^ ((row & 7) << 4)),
              (char*)KsS + row * 1024);
    }
  };

  float m_reg = -3.0e38f, l_reg = 0.f;
  f32x4 acc[4];
  #pragma unroll
  for (int f = 0; f < 4; ++f) acc[f] = (f32x4){0.f, 0.f, 0.f, 0.f};

  stage_k(tbase);
  asm volatile("s_waitcnt vmcnt(0)" ::: "memory");
  __syncthreads();

  u16* PsW = PsS + w * 576;  // warp-private [16][36]
  const int kswz = (lrow & 7) << 4;
  const u16* vwb = vwt + (size_t)b * 64 * SS;

  #pragma unroll 1
  for (int it = 0; it < NQT; ++it) {
    const int t0 = tbase + it * KVBLK;

    // mask for this tile (issued early)
    const size_t mrow = ((size_t)b * SS + qrow) * SS + (size_t)t0;
    const float4 cA = *(const float4*)&mask[mrow + lhi * 4];
    const float4 cB = *(const float4*)&mask[mrow + 16 + lhi * 4];

    // --- QK^T swapped (2 chains): s holds S^T for q-row `qrow` ---
    f32x4 s0 = (f32x4){0.f, 0.f, 0.f, 0.f};
    f32x4 s1 = (f32x4){0.f, 0.f, 0.f, 0.f};
    {
      const char* kp0 = (const char*)KsS + lrow * 1024;
      const char* kp1 = kp0 + 16384;
      __builtin_amdgcn_s_setprio(1);
      #pragma unroll
      for (int kk = 0; kk < 16; ++kk) {
        int off = kk * 64 + lhi * 16;
        f16x8 k0 = *(const f16x8*)(kp0 + (off ^ kswz));
        f16x8 k1 = *(const f16x8*)(kp1 + (off ^ kswz));
        s0 = __builtin_amdgcn_mfma_f32_16x16x32_f16(k0, qreg[kk], s0, 0, 0, 0);
        s1 = __builtin_amdgcn_mfma_f32_16x16x32_f16(k1, qreg[kk], s1, 0, 0, 0);
      }
      __builtin_amdgcn_s_setprio(0);
    }
    __syncthreads();  // B1: all warps done reading KsS

    // stage next K tile immediately (latency hides under softmax+PV)
    if (it + 1 < NQT) stage_k(t0 + KVBLK);

    s0[0] += cA.x; s0[1] += cA.y; s0[2] += cA.z; s0[3] += cA.w;
    s1[0] += cB.x; s1[1] += cB.y; s1[2] += cB.z; s1[3] += cB.w;

    // --- in-warp softmax ---
    float pmax = fmaxf(fmaxf(fmaxf(s0[0], s0[1]), fmaxf(s0[2], s0[3])),
                       fmaxf(fmaxf(s1[0], s1[1]), fmaxf(s1[2], s1[3])));
    pmax = fmaxf(pmax, __shfl_xor(pmax, 16));
    pmax = fmaxf(pmax, __shfl_xor(pmax, 32));

    if (__any(pmax - m_reg > 8.0f)) {  // defer-max (T13)
      float mn = fmaxf(m_reg, pmax);
      float al = __expf(m_reg - mn);
      m_reg = mn;
      l_reg *= al;
      float av[4];
      #pragma unroll
      for (int r = 0; r < 4; ++r) av[r] = __shfl(al, lhi * 4 + r);
      #pragma unroll
      for (int f = 0; f < 4; ++f)
        #pragma unroll
        for (int r = 0; r < 4; ++r) acc[f][r] *= av[r];
    }

    float p[8];
    #pragma unroll
    for (int r = 0; r < 4; ++r) p[r] = __expf(s0[r] - m_reg);
    #pragma unroll
    for (int r = 0; r < 4; ++r) p[4 + r] = __expf(s1[r] - m_reg);
    float psum = ((p[0] + p[1]) + (p[2] + p[3])) + ((p[4] + p[5]) + (p[6] + p[7]));
    psum += __shfl_xor(psum, 16);
    psum += __shfl_xor(psum, 32);
    l_reg += psum;

    // --- VW fragments for this tile (L2 reads, issued before Ps roundtrip) ---
    uint4 vwf[4];
    #pragma unroll
    for (int f = 0; f < 4; ++f)
      vwf[f] = *(const uint4*)(vwb + ((size_t)(lrow + 16 * f)) * SS + t0 + lhi * 8);

    // --- P -> warp-private LDS roundtrip (layout fix, no barrier) ---
    {
      uint2 pw0, pw1;
      pw0.x = (u32)f2h(p[0]) | ((u32)f2h(p[1]) << 16);
      pw0.y = (u32)f2h(p[2]) | ((u32)f2h(p[3]) << 16);
      pw1.x = (u32)f2h(p[4]) | ((u32)f2h(p[5]) << 16);
      pw1.y = (u32)f2h(p[6]) | ((u32)f2h(p[7]) << 16);
      *(uint2*)&PsW[lrow * 36 + lhi * 4] = pw0;
      *(uint2*)&PsW[lrow * 36 + 16 + lhi * 4] = pw1;
    }
    f16x8 pa = *(const f16x8*)&PsW[lrow * 36 + lhi * 8];

    // --- PV: O += P @ VW (d=64 -> 4 MFMA) ---
    #pragma unroll
    for (int f = 0; f < 4; ++f) {
      f16x8 bfr = __builtin_bit_cast(f16x8, vwf[f]);
      acc[f] = __builtin_amdgcn_mfma_f32_16x16x32_f16(pa, bfr, acc[f], 0, 0, 0);
    }

    asm volatile("s_waitcnt vmcnt(0)" ::: "memory");
    __syncthreads();  // B2: KsS(it+1) visible
  }

  // ---- epilogue: normalized partial (fp32) + (m, l) stats ----
  if (lhi == 0) {
    float2* st = (float2*)stats;
    st[(size_t)qt * (BB * SS) + (size_t)b * SS + q0 + w * 16 + lrow] =
        make_float2(m_reg, l_reg);
  }
  float rl[4];
  #pragma unroll
  for (int r = 0; r < 4; ++r) rl[r] = 1.0f / __shfl(l_reg, lhi * 4 + r);
  #pragma unroll
  for (int r = 0; r < 4; ++r) {
    size_t base = ((size_t)qt * (BB * SS) + (size_t)b * SS +
                   (size_t)(q0 + w * 16 + lhi * 4 + r)) * 64 + (size_t)lrow;
    #pragma unroll
    for (int f = 0; f < 4; ++f) opart[base + f * 16] = acc[f][r] * rl[r];
  }
}

// ---------------- K3: merge 4 KV-quarters, add bo ----------------
__global__ __launch_bounds__(256) void merge4(
    const float* __restrict__ opart, const float* __restrict__ stats,
    const float* __restrict__ bo, float* __restrict__ out) {
  const int gid = blockIdx.x * 256 + threadIdx.x;
  const int row = gid >> 3;
  const int c8 = (gid & 7) * 8;
  const float2* st = (const float2*)stats;
  float2 sq[4];
  #pragma unroll
  for (int q = 0; q < 4; ++q) sq[q] = st[(size_t)q * (BB * SS) + row];
  float M = fmaxf(fmaxf(sq[0].x, sq[1].x), fmaxf(sq[2].x, sq[3].x));
  float wv[4], Ssum = 0.f;
  #pragma unroll
  for (int q = 0; q < 4; ++q) {
    wv[q] = __expf(sq[q].x - M) * sq[q].y;
    Ssum += wv[q];
  }
  const float inv = 0.35355339059327373f / Ssum;
  #pragma unroll
  for (int q = 0; q < 4; ++q) wv[q] *= inv;

  float o[8];
  #pragma unroll
  for (int j = 0; j < 8; ++j) o[j] = bo[c8 + j];
  #pragma unroll
  for (int q = 0; q < 4; ++q) {
    const float* op = opart + ((size_t)q * (BB * SS) + row) * 64 + c8;
    float4 a = *(const float4*)op;
    float4 bq4 = *(const float4*)(op + 4);
    o[0] += wv[q] * a.x; o[1] += wv[q] * a.y; o[2] += wv[q] * a.z; o[3] += wv[q] * a.w;
    o[4] += wv[q] * bq4.x; o[5] += wv[q] * bq4.y; o[6] += wv[q] * bq4.z; o[7] += wv[q] * bq4.w;
  }
  float* dst = out + (size_t)row * EE + c8;
  *(float4*)dst = make_float4(o[0], o[1], o[2], o[3]);
  *(float4*)(dst + 4) = make_float4(o[4], o[5], o[6], o[7]);
}

extern "C" void kernel_launch(void* const* d_in, const int* in_sizes, int n_in,
                              void* d_out, int out_size, void* d_ws, size_t ws_size,
                              hipStream_t stream) {
  const float* x = (const float*)d_in[0];
  const float* mask = (const float*)d_in[1];
  const float* Wq = (const float*)d_in[2];
  const float* bq = (const float*)d_in[3];
  const float* Wk = (const float*)d_in[4];
  const float* bk = (const float*)d_in[5];
  const float* Wv = (const float*)d_in[6];
  const float* bv = (const float*)d_in[7];
  const float* Wo = (const float*)d_in[8];
  const float* bo = (const float*)d_in[9];
  float* out = (float*)d_out;

  const size_t N = (size_t)BB * SS * DD;      // 8.4M
  u16* qb = (u16*)d_ws;
  u16* kb = qb + N;
  u16* vwt = kb + N;                          // BB*64*SS u16
  float* Wf = (float*)(vwt + (size_t)BB * 64 * SS);
  float* bf = Wf + 64 * 64;
  float* opart = bf + 64;                     // 4 * BB*SS*64 f32
  float* st = opart + (size_t)4 * BB * SS * 64;  // 4 * BB*SS float2

  qk_proj<<<dim3(BB * SS / 32, 2), 256, 0, stream>>>(x, Wq, bq, Wk, bk, qb, kb);
  wfuse<<<1, 256, 0, stream>>>(Wv, bv, Wo, Wf, bf);
  vw_proj<<<BB * SS / 64, 256, 0, stream>>>(x, Wf, bf, vwt);
  attn_fwd<<<1024, 256, 0, stream>>>(qb, kb, vwt, mask, opart, st);
  merge4<<<BB * SS * 8 / 256, 256, 0, stream>>>(opart, st, bo, out);
}

// Round 10
// 346.119 us; speedup vs baseline: 1.8572x; 1.8572x over previous
//
#include <hip/hip_runtime.h>
#include <hip/hip_bf16.h>

#define BB 4
#define SS 4096
#define EE 64
#define DD 512
#define KVBLK 32
#define NQT 32  // KV tiles per quarter

typedef __attribute__((ext_vector_type(4))) float f32x4;
typedef __attribute__((ext_vector_type(8))) _Float16 f16x8;
typedef unsigned short u16;
typedef unsigned int u32;

__device__ __forceinline__ u16 f2h(float f) {
  _Float16 h = (_Float16)f;
  return __builtin_bit_cast(u16, h);
}
__device__ __forceinline__ float h2f(u16 b) {
  return (float)__builtin_bit_cast(_Float16, b);
}

__device__ __forceinline__ void async16(const void* g, void* l) {
  __builtin_amdgcn_global_load_lds(
      (const __attribute__((address_space(1))) void*)g,
      (__attribute__((address_space(3))) void*)l, 16, 0, 0);
}

// ---------------- K1: q,k projection (fp32 VALU), emit fp16 ----------------
__global__ __launch_bounds__(256) void qk_proj(
    const float* __restrict__ x,
    const float* __restrict__ Wq, const float* __restrict__ bq,
    const float* __restrict__ Wk, const float* __restrict__ bk,
    u16* __restrict__ qb, u16* __restrict__ kb) {
  __shared__ float xs[32][EE];
  const int tid = threadIdx.x;
  const int row0 = blockIdx.x * 32;
  const float* W = blockIdx.y ? Wk : Wq;
  const float* bias = blockIdx.y ? bk : bq;
  u16* dst = blockIdx.y ? kb : qb;

  #pragma unroll
  for (int i = 0; i < 2; ++i) {
    int idx = tid + 256 * i;
    int r = idx >> 4, c = (idx & 15) * 4;
    *(float4*)&xs[r][c] = *(const float4*)&x[(size_t)(row0 + r) * EE + c];
  }
  __syncthreads();

  const int col = (tid & 127) * 4;
  const int rg = (tid >> 7) * 16;
  float acc[16][4];
  #pragma unroll
  for (int r = 0; r < 16; ++r)
    #pragma unroll
    for (int j = 0; j < 4; ++j) acc[r][j] = 0.f;

  for (int k = 0; k < EE; k += 4) {
    float4 wr[4];
    #pragma unroll
    for (int j = 0; j < 4; ++j) wr[j] = *(const float4*)&W[(size_t)(k + j) * DD + col];
    #pragma unroll
    for (int r = 0; r < 16; ++r) {
      float4 xv = *(const float4*)&xs[rg + r][k];
      acc[r][0] += xv.x * wr[0].x + xv.y * wr[1].x + xv.z * wr[2].x + xv.w * wr[3].x;
      acc[r][1] += xv.x * wr[0].y + xv.y * wr[1].y + xv.z * wr[2].y + xv.w * wr[3].y;
      acc[r][2] += xv.x * wr[0].z + xv.y * wr[1].z + xv.z * wr[2].z + xv.w * wr[3].z;
      acc[r][3] += xv.x * wr[0].w + xv.y * wr[1].w + xv.z * wr[2].w + xv.w * wr[3].w;
    }
  }

  const float4 b4 = *(const float4*)&bias[col];
  #pragma unroll
  for (int r = 0; r < 16; ++r) {
    ushort4 o;
    o.x = f2h(acc[r][0] + b4.x);
    o.y = f2h(acc[r][1] + b4.y);
    o.z = f2h(acc[r][2] + b4.z);
    o.w = f2h(acc[r][3] + b4.w);
    *(ushort4*)&dst[(size_t)(row0 + rg + r) * DD + col] = o;
  }
}

// ---------------- K1b: Wf = Wv @ Wo (64x64), bf = bv @ Wo — PARALLEL ----------------
// 65 blocks: block e<64 computes Wf[e][*]; block 64 computes bf.
// thread = (d = tid&63, k-quarter = tid>>6); coalesced Wo reads; LDS reduce.
__global__ __launch_bounds__(256) void wfuse(
    const float* __restrict__ Wv, const float* __restrict__ bv,
    const float* __restrict__ Wo, float* __restrict__ Wf, float* __restrict__ bf) {
  __shared__ float red[4][64];
  const int tid = threadIdx.x;
  const int d = tid & 63, kq = tid >> 6;
  const int e = blockIdx.x;
  const float* src = (e < 64) ? &Wv[(size_t)e * DD] : bv;
  float a = 0.f;
  #pragma unroll 4
  for (int k = kq * 128; k < (kq + 1) * 128; ++k)
    a += src[k] * Wo[(size_t)k * EE + d];
  red[kq][d] = a;
  __syncthreads();
  if (tid < 64) {
    float s = (red[0][tid] + red[1][tid]) + (red[2][tid] + red[3][tid]);
    if (e < 64) Wf[e * EE + tid] = s;
    else bf[tid] = s;
  }
}

// ---------------- K1c: VWt[b][d][s] = (x @ Wf + bf)^T, fp16 ----------------
__global__ __launch_bounds__(256) void vw_proj(
    const float* __restrict__ x, const float* __restrict__ Wf,
    const float* __restrict__ bf, u16* __restrict__ vwt) {
  __shared__ float xs[64][EE];
  __shared__ float wfs[EE][64];
  __shared__ float bfs[64];
  const int tid = threadIdx.x;
  const int b = blockIdx.x & 3;
  const int s0 = (blockIdx.x >> 2) * 64;

  #pragma unroll
  for (int i = 0; i < 4; ++i) {
    int idx = tid + 256 * i;
    int r = idx >> 4, c = (idx & 15) * 4;
    *(float4*)&xs[r][c] = *(const float4*)&x[((size_t)b * SS + s0 + r) * EE + c];
    *(float4*)&wfs[r][c] = *(const float4*)&Wf[(size_t)r * 64 + c];
  }
  if (tid < 64) bfs[tid] = bf[tid];
  __syncthreads();

  const int d = tid & 63, sg = tid >> 6;
  float acc[16];
  #pragma unroll
  for (int i = 0; i < 16; ++i) acc[i] = bfs[d];
  for (int e = 0; e < EE; ++e) {
    float wv = wfs[e][d];
    #pragma unroll
    for (int i = 0; i < 16; ++i) acc[i] += xs[sg * 16 + i][e] * wv;
  }
  u16* dst = vwt + ((size_t)b * 64 + d) * SS + s0 + sg * 16;
  union { uint4 u[2]; u16 hh[16]; } o;
  #pragma unroll
  for (int i = 0; i < 16; ++i) o.hh[i] = f2h(acc[i]);
  *(uint4*)dst = o.u[0];
  *(uint4*)(dst + 8) = o.u[1];
}

// ---------------- K2: flash attention v7 (fused VW, d=64, 4 blocks/CU) ----------------
// 1024 blocks x 256 thr (4 warps x 16q = 64 q-rows). bid&15 = (batch, kv-quarter).
// Q in regs; swapped QK^T; warp-private softmax; PV vs VW (d=64) from L2;
// K single-buffered async16, staged right after QK-reads barrier.
__global__ __launch_bounds__(256, 4) void attn_fwd(
    const u16* __restrict__ qbuf, const u16* __restrict__ kbuf,
    const u16* __restrict__ vwt, const float* __restrict__ mask,
    float* __restrict__ opart, float* __restrict__ stats) {
  __shared__ u16 KsS[32 * 512];       // 32768 B
  __shared__ u16 PsS[4 * 16 * 36];    // 4608 B

  const int tid = threadIdx.x;
  const int lane = tid & 63;
  const int w = tid >> 6;  // 0..3
  const int lrow = lane & 15, lhi = lane >> 4;

  const int bid = blockIdx.x;
  const int grp = bid & 15;
  const int b = grp >> 2, qt = grp & 3;
  const int q0 = (bid >> 4) * 64;
  const int tbase = qt * (SS / 4);

  const int qrow = q0 + w * 16 + lrow;

  // ---- Q -> registers (B-operand frags) ----
  f16x8 qreg[16];
  {
    const u16* qg = qbuf + ((size_t)b * SS + qrow) * DD + lhi * 8;
    #pragma unroll
    for (int kk = 0; kk < 16; ++kk) qreg[kk] = *(const f16x8*)(qg + kk * 32);
  }

  auto stage_k = [&](int t0n) {
    const char* kg = (const char*)(kbuf + ((size_t)b * SS + t0n) * DD);
    #pragma unroll
    for (int rr = 0; rr < 8; ++rr) {
      int row = w * 8 + rr;
      async16(kg + (size_t)row * 1024 + ((lane * 16) ^ ((row & 7) << 4)),
              (char*)KsS + row * 1024);
    }
  };

  float m_reg = -3.0e38f, l_reg = 0.f;
  f32x4 acc[4];
  #pragma unroll
  for (int f = 0; f < 4; ++f) acc[f] = (f32x4){0.f, 0.f, 0.f, 0.f};

  stage_k(tbase);
  asm volatile("s_waitcnt vmcnt(0)" ::: "memory");
  __syncthreads();

  u16* PsW = PsS + w * 576;  // warp-private [16][36]
  const int kswz = (lrow & 7) << 4;
  const u16* vwb = vwt + (size_t)b * 64 * SS;

  #pragma unroll 1
  for (int it = 0; it < NQT; ++it) {
    const int t0 = tbase + it * KVBLK;

    // mask for this tile (issued early)
    const size_t mrow = ((size_t)b * SS + qrow) * SS + (size_t)t0;
    const float4 cA = *(const float4*)&mask[mrow + lhi * 4];
    const float4 cB = *(const float4*)&mask[mrow + 16 + lhi * 4];

    // --- QK^T swapped (2 chains): s holds S^T for q-row `qrow` ---
    f32x4 s0 = (f32x4){0.f, 0.f, 0.f, 0.f};
    f32x4 s1 = (f32x4){0.f, 0.f, 0.f, 0.f};
    {
      const char* kp0 = (const char*)KsS + lrow * 1024;
      const char* kp1 = kp0 + 16384;
      __builtin_amdgcn_s_setprio(1);
      #pragma unroll
      for (int kk = 0; kk < 16; ++kk) {
        int off = kk * 64 + lhi * 16;
        f16x8 k0 = *(const f16x8*)(kp0 + (off ^ kswz));
        f16x8 k1 = *(const f16x8*)(kp1 + (off ^ kswz));
        s0 = __builtin_amdgcn_mfma_f32_16x16x32_f16(k0, qreg[kk], s0, 0, 0, 0);
        s1 = __builtin_amdgcn_mfma_f32_16x16x32_f16(k1, qreg[kk], s1, 0, 0, 0);
      }
      __builtin_amdgcn_s_setprio(0);
    }
    __syncthreads();  // B1: all warps done reading KsS

    // stage next K tile immediately (latency hides under softmax+PV)
    if (it + 1 < NQT) stage_k(t0 + KVBLK);

    s0[0] += cA.x; s0[1] += cA.y; s0[2] += cA.z; s0[3] += cA.w;
    s1[0] += cB.x; s1[1] += cB.y; s1[2] += cB.z; s1[3] += cB.w;

    // --- in-warp softmax ---
    float pmax = fmaxf(fmaxf(fmaxf(s0[0], s0[1]), fmaxf(s0[2], s0[3])),
                       fmaxf(fmaxf(s1[0], s1[1]), fmaxf(s1[2], s1[3])));
    pmax = fmaxf(pmax, __shfl_xor(pmax, 16));
    pmax = fmaxf(pmax, __shfl_xor(pmax, 32));

    if (__any(pmax - m_reg > 8.0f)) {  // defer-max (T13)
      float mn = fmaxf(m_reg, pmax);
      float al = __expf(m_reg - mn);
      m_reg = mn;
      l_reg *= al;
      float av[4];
      #pragma unroll
      for (int r = 0; r < 4; ++r) av[r] = __shfl(al, lhi * 4 + r);
      #pragma unroll
      for (int f = 0; f < 4; ++f)
        #pragma unroll
        for (int r = 0; r < 4; ++r) acc[f][r] *= av[r];
    }

    float p[8];
    #pragma unroll
    for (int r = 0; r < 4; ++r) p[r] = __expf(s0[r] - m_reg);
    #pragma unroll
    for (int r = 0; r < 4; ++r) p[4 + r] = __expf(s1[r] - m_reg);
    float psum = ((p[0] + p[1]) + (p[2] + p[3])) + ((p[4] + p[5]) + (p[6] + p[7]));
    psum += __shfl_xor(psum, 16);
    psum += __shfl_xor(psum, 32);
    l_reg += psum;

    // --- VW fragments for this tile (L2 reads, issued before Ps roundtrip) ---
    uint4 vwf[4];
    #pragma unroll
    for (int f = 0; f < 4; ++f)
      vwf[f] = *(const uint4*)(vwb + ((size_t)(lrow + 16 * f)) * SS + t0 + lhi * 8);

    // --- P -> warp-private LDS roundtrip (layout fix, no barrier) ---
    {
      uint2 pw0, pw1;
      pw0.x = (u32)f2h(p[0]) | ((u32)f2h(p[1]) << 16);
      pw0.y = (u32)f2h(p[2]) | ((u32)f2h(p[3]) << 16);
      pw1.x = (u32)f2h(p[4]) | ((u32)f2h(p[5]) << 16);
      pw1.y = (u32)f2h(p[6]) | ((u32)f2h(p[7]) << 16);
      *(uint2*)&PsW[lrow * 36 + lhi * 4] = pw0;
      *(uint2*)&PsW[lrow * 36 + 16 + lhi * 4] = pw1;
    }
    f16x8 pa = *(const f16x8*)&PsW[lrow * 36 + lhi * 8];

    // --- PV: O += P @ VW (d=64 -> 4 MFMA) ---
    #pragma unroll
    for (int f = 0; f < 4; ++f) {
      f16x8 bfr = __builtin_bit_cast(f16x8, vwf[f]);
      acc[f] = __builtin_amdgcn_mfma_f32_16x16x32_f16(pa, bfr, acc[f], 0, 0, 0);
    }

    asm volatile("s_waitcnt vmcnt(0)" ::: "memory");
    __syncthreads();  // B2: KsS(it+1) visible
  }

  // ---- epilogue: normalized partial (fp32) + (m, l) stats ----
  if (lhi == 0) {
    float2* st = (float2*)stats;
    st[(size_t)qt * (BB * SS) + (size_t)b * SS + q0 + w * 16 + lrow] =
        make_float2(m_reg, l_reg);
  }
  float rl[4];
  #pragma unroll
  for (int r = 0; r < 4; ++r) rl[r] = 1.0f / __shfl(l_reg, lhi * 4 + r);
  #pragma unroll
  for (int r = 0; r < 4; ++r) {
    size_t base = ((size_t)qt * (BB * SS) + (size_t)b * SS +
                   (size_t)(q0 + w * 16 + lhi * 4 + r)) * 64 + (size_t)lrow;
    #pragma unroll
    for (int f = 0; f < 4; ++f) opart[base + f * 16] = acc[f][r] * rl[r];
  }
}

// ---------------- K3: merge 4 KV-quarters, add bo ----------------
__global__ __launch_bounds__(256) void merge4(
    const float* __restrict__ opart, const float* __restrict__ stats,
    const float* __restrict__ bo, float* __restrict__ out) {
  const int gid = blockIdx.x * 256 + threadIdx.x;
  const int row = gid >> 3;
  const int c8 = (gid & 7) * 8;
  const float2* st = (const float2*)stats;
  float2 sq[4];
  #pragma unroll
  for (int q = 0; q < 4; ++q) sq[q] = st[(size_t)q * (BB * SS) + row];
  float M = fmaxf(fmaxf(sq[0].x, sq[1].x), fmaxf(sq[2].x, sq[3].x));
  float wv[4], Ssum = 0.f;
  #pragma unroll
  for (int q = 0; q < 4; ++q) {
    wv[q] = __expf(sq[q].x - M) * sq[q].y;
    Ssum += wv[q];
  }
  const float inv = 0.35355339059327373f / Ssum;
  #pragma unroll
  for (int q = 0; q < 4; ++q) wv[q] *= inv;

  float o[8];
  #pragma unroll
  for (int j = 0; j < 8; ++j) o[j] = bo[c8 + j];
  #pragma unroll
  for (int q = 0; q < 4; ++q) {
    const float* op = opart + ((size_t)q * (BB * SS) + row) * 64 + c8;
    float4 a = *(const float4*)op;
    float4 bq4 = *(const float4*)(op + 4);
    o[0] += wv[q] * a.x; o[1] += wv[q] * a.y; o[2] += wv[q] * a.z; o[3] += wv[q] * a.w;
    o[4] += wv[q] * bq4.x; o[5] += wv[q] * bq4.y; o[6] += wv[q] * bq4.z; o[7] += wv[q] * bq4.w;
  }
  float* dst = out + (size_t)row * EE + c8;
  *(float4*)dst = make_float4(o[0], o[1], o[2], o[3]);
  *(float4*)(dst + 4) = make_float4(o[4], o[5], o[6], o[7]);
}

extern "C" void kernel_launch(void* const* d_in, const int* in_sizes, int n_in,
                              void* d_out, int out_size, void* d_ws, size_t ws_size,
                              hipStream_t stream) {
  const float* x = (const float*)d_in[0];
  const float* mask = (const float*)d_in[1];
  const float* Wq = (const float*)d_in[2];
  const float* bq = (const float*)d_in[3];
  const float* Wk = (const float*)d_in[4];
  const float* bk = (const float*)d_in[5];
  const float* Wv = (const float*)d_in[6];
  const float* bv = (const float*)d_in[7];
  const float* Wo = (const float*)d_in[8];
  const float* bo = (const float*)d_in[9];
  float* out = (float*)d_out;

  const size_t N = (size_t)BB * SS * DD;      // 8.4M
  u16* qb = (u16*)d_ws;
  u16* kb = qb + N;
  u16* vwt = kb + N;                          // BB*64*SS u16
  float* Wf = (float*)(vwt + (size_t)BB * 64 * SS);
  float* bf = Wf + 64 * 64;
  float* opart = bf + 64;                     // 4 * BB*SS*64 f32
  float* st = opart + (size_t)4 * BB * SS * 64;  // 4 * BB*SS float2

  qk_proj<<<dim3(BB * SS / 32, 2), 256, 0, stream>>>(x, Wq, bq, Wk, bk, qb, kb);
  wfuse<<<65, 256, 0, stream>>>(Wv, bv, Wo, Wf, bf);
  vw_proj<<<BB * SS / 64, 256, 0, stream>>>(x, Wf, bf, vwt);
  attn_fwd<<<1024, 256, 0, stream>>>(qb, kb, vwt, mask, opart, st);
  merge4<<<BB * SS * 8 / 256, 256, 0, stream>>>(opart, st, bo, out);
}